// Round 1
// baseline (597.935 us; speedup 1.0000x reference)
//
#include <hip/hip_runtime.h>
#include <hip/hip_bf16.h>

// ============================================================================
// multipole_interaction: fused bf16-MFMA implementation
//
// Scheme: all GEMMs computed transposed:  OUT^T = W^T (A-operand) * X^T (B-op)
//   mfma_f32_16x16x32_bf16 layouts (m89/m97-verified):
//     A: lane holds A[l&15][(l>>4)*8+j]          (row = out-feature)
//     B: lane holds B[(l>>4)*8+j][l&15]          (col = atom)
//     D: lane holds D[(l>>4)*4+r][l&15]          (col = atom)
//   => atom is always lane&15; per-atom T coeffs live in registers.
//
// prep kernel: weights f32 [gin][gout] -> bf16 A-frag layout (W^T) in d_ws.
// main kernel: 128 thr (2 waves), 16 atoms/wave, 3125 blocks (N=100000).
// ============================================================================

typedef short bf16x8 __attribute__((ext_vector_type(8)));
typedef float f32x4  __attribute__((ext_vector_type(4)));
typedef unsigned short u16;

#define EPS 1e-7f
#define LDS_FENCE() asm volatile("s_waitcnt lgkmcnt(0)" ::: "memory")

__device__ __forceinline__ u16 f2bf(float x) {
    union { float f; unsigned u; } un; un.f = x;
    unsigned r = un.u;
    r += 0x7fffu + ((r >> 16) & 1u);   // RTNE
    return (u16)(r >> 16);
}

__device__ __forceinline__ bf16x8 pack8(const float* v) {
    bf16x8 r;
#pragma unroll
    for (int j = 0; j < 8; ++j) r[j] = (short)f2bf(v[j]);
    return r;
}

__device__ __forceinline__ f32x4 mfma(bf16x8 a, bf16x8 b, f32x4 c) {
    return __builtin_amdgcn_mfma_f32_16x16x32_bf16(a, b, c, 0, 0, 0);
}

// ---------------------------------------------------------------------------
// Weight prep: 8 matrices of 128x128 f32 [gin][gout] -> bf16 frags.
// frag elem index = m*16384 + gt*2048 + kc*512 + lane*8 + j
//   holds W[kc*32 + (lane>>4)*8 + j][gt*16 + (lane&15)]
// ---------------------------------------------------------------------------
__global__ void mp_prep(const float* __restrict__ w0, const float* __restrict__ w1,
                        const float* __restrict__ w2, const float* __restrict__ w3,
                        const float* __restrict__ w4, const float* __restrict__ w5,
                        const float* __restrict__ w6, const float* __restrict__ w7,
                        u16* __restrict__ out) {
    int tid = blockIdx.x * 256 + threadIdx.x;
    int m   = tid >> 14;
    int rem = tid & 16383;
    int j  = rem & 7;
    int ln = (rem >> 3) & 63;
    int kc = (rem >> 9) & 3;
    int gt = (rem >> 11) & 7;
    int gin  = kc * 32 + (ln >> 4) * 8 + j;
    int gout = gt * 16 + (ln & 15);
    const float* w = w0;
    if (m == 1) w = w1; else if (m == 2) w = w2; else if (m == 3) w = w3;
    else if (m == 4) w = w4; else if (m == 5) w = w5; else if (m == 6) w = w6;
    else if (m == 7) w = w7;
    out[tid] = f2bf(w[gin * 128 + gout]);
}

// ---------------------------------------------------------------------------
// Main fused kernel
// ---------------------------------------------------------------------------
__global__ __launch_bounds__(128, 2) void mp_main(
    const float* __restrict__ feat, const float* __restrict__ mu,
    const float* __restrict__ T0,   const float* __restrict__ T1,
    const float* __restrict__ T2,   const float* __restrict__ T3,
    const float* __restrict__ bq1,  const float* __restrict__ bq2,
    const float* __restrict__ bs1,  const float* __restrict__ bs2,
    const float* __restrict__ cM1,  const float* __restrict__ cM2,
    const float* __restrict__ cM3,
    const u16* __restrict__ wf, float* __restrict__ out, int N) {

    __shared__ __align__(16) u16 tA [2][2048];      // h / ms / s2 tile, per wave
    __shared__ __align__(16) u16 tMV[2][3][2048];   // mv tiles, per wave
    __shared__ float rT[2][16 * 41];                // raw T per atom (41-stride)

    const int w    = threadIdx.x >> 6;
    const int lane = threadIdx.x & 63;
    const int aIdx = lane & 15;                     // atom (MFMA column)
    const int q    = lane >> 4;
    const int a0   = blockIdx.x * 32 + w * 16;
    const int an   = a0 + aIdx;
    const int anc  = an < N ? an : N - 1;

    u16*   tile = tA[w];
    float* rTw  = rT[w];
    const bf16x8* wfr = (const bf16x8*)wf;          // frag units (8 bf16 = 16B)

    // ---- stage raw T tensors into LDS (stride 41 floats -> conflict-free) --
    for (int e = lane; e < 16;  e += 64) rTw[e * 41]                         = T0[min(a0 + e, N - 1)];
    for (int e = lane; e < 48;  e += 64) rTw[(e / 3)  * 41 + 1  + (e % 3)]   = T1[min(a0 * 3  + e, N * 3  - 1)];
    for (int e = lane; e < 144; e += 64) rTw[(e / 9)  * 41 + 4  + (e % 9)]   = T2[min(a0 * 9  + e, N * 9  - 1)];
    for (int e = lane; e < 432; e += 64) rTw[(e / 27) * 41 + 13 + (e % 27)]  = T3[min(a0 * 27 + e, N * 27 - 1)];

    // ---- feat B-frags --------------------------------------------------------
    bf16x8 featB[4];
    {
        const float* fr = feat + (size_t)anc * 128;
#pragma unroll
        for (int kc = 0; kc < 4; ++kc) {
            float t[8];
            *(float4*)&t[0] = *(const float4*)(fr + kc * 32 + q * 8);
            *(float4*)&t[4] = *(const float4*)(fr + kc * 32 + q * 8 + 4);
            featB[kc] = pack8(t);
        }
    }

    // ---- h = swish(feat@Wq1 + bq1)  -> tile (bf16, swizzled) ----------------
#pragma unroll
    for (int gt = 0; gt < 8; ++gt) {
        f32x4 acc = {0.f, 0.f, 0.f, 0.f};
#pragma unroll
        for (int kc = 0; kc < 4; ++kc)
            acc = mfma(wfr[0 * 2048 + (gt * 4 + kc) * 64 + lane], featB[kc], acc);
        float4 b = *(const float4*)(bq1 + gt * 16 + q * 4);
        float hv[4];
#pragma unroll
        for (int r = 0; r < 4; ++r) {
            float xv = acc[r] + ((const float*)&b)[r];
            hv[r] = xv * __builtin_amdgcn_rcpf(1.f + __expf(-xv));
        }
        int byte = gt * 32 + q * 8;
        int slot = (byte >> 4) ^ (aIdx & 7);
        *(ushort4*)((char*)tile + aIdx * 256 + slot * 16 + (byte & 15)) =
            make_ushort4(f2bf(hv[0]), f2bf(hv[1]), f2bf(hv[2]), f2bf(hv[3]));
    }

    LDS_FENCE();   // T-stage + h writes now visible to this wave's reads

    // ---- h B-frags -----------------------------------------------------------
    bf16x8 hB[4];
#pragma unroll
    for (int kc = 0; kc < 4; ++kc) {
        int byte = kc * 64 + q * 16;
        int slot = (byte >> 4) ^ (aIdx & 7);
        hB[kc] = *(const bf16x8*)((char*)tile + aIdx * 256 + slot * 16);
    }

    // ---- mu B-frags (scalar stride-3 loads; raw mu read = 153.6 MB) ---------
    bf16x8 muB[3][4];
    {
        const float* mr = mu + (size_t)anc * 384;
#pragma unroll
        for (int i = 0; i < 3; ++i)
#pragma unroll
            for (int kc = 0; kc < 4; ++kc) {
                float t[8];
#pragma unroll
                for (int j = 0; j < 8; ++j) t[j] = mr[(kc * 32 + q * 8 + j) * 3 + i];
                muB[i][kc] = pack8(t);
            }
    }

    // ---- per-lane multipole coefficients (this lane's atom = aIdx) ----------
    const float* rt = rTw + aIdx * 41;
    const float  T0v = rt[0];
    const float  T1x = rt[1], T1y = rt[2], T1z = rt[3];
    float t2[9];
#pragma unroll
    for (int j = 0; j < 9; ++j) t2[j] = rt[4 + j];
    // ms quadratic (symmetrized, acts on M2)
    const float Q00 = t2[0], Q11 = t2[4], Q22 = t2[8];
    const float Q01 = t2[1] + t2[3], Q02 = t2[2] + t2[6], Q12 = t2[5] + t2[7];
    const float* r3 = rt + 13;
    // ms cubic (symmetrized, acts on M3)
    const float C300 = r3[0],  C030 = r3[13], C003 = r3[26];
    const float C210 = r3[1]  + r3[3]  + r3[9];
    const float C201 = r3[2]  + r3[6]  + r3[18];
    const float C120 = r3[4]  + r3[10] + r3[12];
    const float C021 = r3[14] + r3[16] + r3[22];
    const float C102 = r3[8]  + r3[20] + r3[24];
    const float C012 = r3[17] + r3[23] + r3[25];
    const float C111 = r3[5] + r3[7] + r3[11] + r3[15] + r3[19] + r3[21];
    // mv octupole (symmetrized in jk, acts on M2), per output comp i
    float D00[3], D01[3], D02[3], D11[3], D12[3], D22[3];
#pragma unroll
    for (int i = 0; i < 3; ++i) {
        D00[i] = r3[9 * i];
        D01[i] = r3[9 * i + 1] + r3[9 * i + 3];
        D02[i] = r3[9 * i + 2] + r3[9 * i + 6];
        D11[i] = r3[9 * i + 4];
        D12[i] = r3[9 * i + 5] + r3[9 * i + 7];
        D22[i] = r3[9 * i + 8];
    }

    // ---- main loop over output-feature tiles --------------------------------
    for (int gt = 0; gt < 8; ++gt) {
        f32x4 M0a = {0.f, 0.f, 0.f, 0.f};
#pragma unroll
        for (int kc = 0; kc < 4; ++kc)
            M0a = mfma(wfr[1 * 2048 + (gt * 4 + kc) * 64 + lane], hB[kc], M0a);

        f32x4 mraw[3][3];
#pragma unroll
        for (int t = 0; t < 3; ++t)
#pragma unroll
            for (int i = 0; i < 3; ++i) mraw[t][i] = (f32x4){0.f, 0.f, 0.f, 0.f};
#pragma unroll
        for (int t = 0; t < 3; ++t)
#pragma unroll
            for (int kc = 0; kc < 4; ++kc) {
                bf16x8 wt = wfr[(2 + t) * 2048 + (gt * 4 + kc) * 64 + lane];
#pragma unroll
                for (int i = 0; i < 3; ++i) mraw[t][i] = mfma(wt, muB[i][kc], mraw[t][i]);
            }

        float4 bq  = *(const float4*)(bq2 + gt * 16 + q * 4);
        float4 c1v = *(const float4*)(cM1 + gt * 16 + q * 4);
        float4 c2v = *(const float4*)(cM2 + gt * 16 + q * 4);
        float4 c3v = *(const float4*)(cM3 + gt * 16 + q * 4);

        float msv[4], mvv[3][4];
#pragma unroll
        for (int r = 0; r < 4; ++r) {
            float m0 = M0a[r] + ((const float*)&bq)[r];
            float Mn[3][3];
#pragma unroll
            for (int t = 0; t < 3; ++t) {
                float cc = ((const float*)(t == 0 ? &c1v : (t == 1 ? &c2v : &c3v)))[r];
                cc = cc * cc;
                float e0 = mraw[t][0][r] + EPS;
                float e1 = mraw[t][1][r] + EPS;
                float e2 = mraw[t][2][r] + EPS;
                float s  = e0 * e0 + e1 * e1 + e2 * e2;
                float rs = __builtin_amdgcn_rsqf(s);
                float den = cc * (s * rs) + 1.f;         // c^2 * ||M+eps|| + 1
                float inv = __builtin_amdgcn_rcpf(den);
                Mn[t][0] = mraw[t][0][r] * inv;
                Mn[t][1] = mraw[t][1][r] * inv;
                Mn[t][2] = mraw[t][2][r] * inv;
            }
            const float p  = Mn[0][0], pq = Mn[0][1], pr = Mn[0][2];   // M1
            const float u  = Mn[1][0], v  = Mn[1][1], w2 = Mn[1][2];   // M2
            const float x  = Mn[2][0], y  = Mn[2][1], z  = Mn[2][2];   // M3
            float ms = T0v * m0 + T1x * p + T1y * pq + T1z * pr;
            ms += u * (Q00 * u + Q01 * v + Q02 * w2) + v * (Q11 * v + Q12 * w2) + Q22 * w2 * w2;
            float x2 = x * x, y2 = y * y, z2 = z * z;
            ms += x2 * (C300 * x + C210 * y + C201 * z)
                + y2 * (C120 * x + C030 * y + C021 * z)
                + z2 * (C102 * x + C012 * y + C003 * z)
                + C111 * (x * y * z);
            msv[r] = ms;
            float uu = u * u, vv = v * v, ww = w2 * w2;
            float uv = u * v, uw = u * w2, vw = v * w2;
#pragma unroll
            for (int i = 0; i < 3; ++i) {
                float t1i = (i == 0 ? T1x : (i == 1 ? T1y : T1z));
                mvv[i][r] = t1i * m0
                          + t2[3 * i] * p + t2[3 * i + 1] * pq + t2[3 * i + 2] * pr
                          + D00[i] * uu + D01[i] * uv + D02[i] * uw
                          + D11[i] * vv + D12[i] * vw + D22[i] * ww;
            }
        }
        int byte = gt * 32 + q * 8;
        int slot = (byte >> 4) ^ (aIdx & 7);
        int off  = aIdx * 256 + slot * 16 + (byte & 15);
        *(ushort4*)((char*)tile + off) =
            make_ushort4(f2bf(msv[0]), f2bf(msv[1]), f2bf(msv[2]), f2bf(msv[3]));
#pragma unroll
        for (int i = 0; i < 3; ++i)
            *(ushort4*)((char*)tMV[w][i] + off) =
                make_ushort4(f2bf(mvv[i][0]), f2bf(mvv[i][1]), f2bf(mvv[i][2]), f2bf(mvv[i][3]));
    }

    LDS_FENCE();

    // ---- ms / mv B-frags ----------------------------------------------------
    bf16x8 msB[4], mvB[3][4];
#pragma unroll
    for (int kc = 0; kc < 4; ++kc) {
        int byte = kc * 64 + q * 16;
        int slot = (byte >> 4) ^ (aIdx & 7);
        msB[kc] = *(const bf16x8*)((char*)tile + aIdx * 256 + slot * 16);
#pragma unroll
        for (int i = 0; i < 3; ++i)
            mvB[i][kc] = *(const bf16x8*)((char*)tMV[w][i] + aIdx * 256 + slot * 16);
    }

    // ---- s2 = swish(ms@Ws1 + bs1) -> tile -----------------------------------
#pragma unroll
    for (int gt = 0; gt < 8; ++gt) {
        f32x4 acc = {0.f, 0.f, 0.f, 0.f};
#pragma unroll
        for (int kc = 0; kc < 4; ++kc)
            acc = mfma(wfr[5 * 2048 + (gt * 4 + kc) * 64 + lane], msB[kc], acc);
        float4 b = *(const float4*)(bs1 + gt * 16 + q * 4);
        float hv[4];
#pragma unroll
        for (int r = 0; r < 4; ++r) {
            float xv = acc[r] + ((const float*)&b)[r];
            hv[r] = xv * __builtin_amdgcn_rcpf(1.f + __expf(-xv));
        }
        int byte = gt * 32 + q * 8;
        int slot = (byte >> 4) ^ (aIdx & 7);
        *(ushort4*)((char*)tile + aIdx * 256 + slot * 16 + (byte & 15)) =
            make_ushort4(f2bf(hv[0]), f2bf(hv[1]), f2bf(hv[2]), f2bf(hv[3]));
    }

    LDS_FENCE();

    bf16x8 s2B[4];
#pragma unroll
    for (int kc = 0; kc < 4; ++kc) {
        int byte = kc * 64 + q * 16;
        int slot = (byte >> 4) ^ (aIdx & 7);
        s2B[kc] = *(const bf16x8*)((char*)tile + aIdx * 256 + slot * 16);
    }

    // ---- ms_out = s2@Ws2 + bs2 ----------------------------------------------
#pragma unroll
    for (int gt = 0; gt < 8; ++gt) {
        f32x4 acc = {0.f, 0.f, 0.f, 0.f};
#pragma unroll
        for (int kc = 0; kc < 4; ++kc)
            acc = mfma(wfr[6 * 2048 + (gt * 4 + kc) * 64 + lane], s2B[kc], acc);
        float4 b = *(const float4*)(bs2 + gt * 16 + q * 4);
        if (an < N) {
            float4 o;
            o.x = acc[0] + b.x; o.y = acc[1] + b.y;
            o.z = acc[2] + b.z; o.w = acc[3] + b.w;
            *(float4*)(out + (size_t)an * 128 + gt * 16 + q * 4) = o;
        }
    }

    // ---- mv_out = mv@Wv  (N*A f32 offset; [n][a][i] layout) -----------------
    float* omv = out + (size_t)N * 128;
#pragma unroll
    for (int gt = 0; gt < 8; ++gt) {
        bf16x8 wv[4];
#pragma unroll
        for (int kc = 0; kc < 4; ++kc) wv[kc] = wfr[7 * 2048 + (gt * 4 + kc) * 64 + lane];
#pragma unroll
        for (int i = 0; i < 3; ++i) {
            f32x4 acc = {0.f, 0.f, 0.f, 0.f};
#pragma unroll
            for (int kc = 0; kc < 4; ++kc) acc = mfma(wv[kc], mvB[i][kc], acc);
            if (an < N) {
#pragma unroll
                for (int r = 0; r < 4; ++r)
                    omv[(size_t)an * 384 + (gt * 16 + q * 4 + r) * 3 + i] = acc[r];
            }
        }
    }
}

// ---------------------------------------------------------------------------
extern "C" void kernel_launch(void* const* d_in, const int* in_sizes, int n_in,
                              void* d_out, int out_size, void* d_ws, size_t ws_size,
                              hipStream_t stream) {
    const float* feat = (const float*)d_in[0];
    const float* mu   = (const float*)d_in[1];
    const float* T0   = (const float*)d_in[2];
    const float* T1   = (const float*)d_in[3];
    const float* T2   = (const float*)d_in[4];
    const float* T3   = (const float*)d_in[5];
    const float* Wq1  = (const float*)d_in[6];
    const float* bq1  = (const float*)d_in[7];
    const float* Wq2  = (const float*)d_in[8];
    const float* bq2  = (const float*)d_in[9];
    const float* WT1  = (const float*)d_in[10];
    const float* WT2  = (const float*)d_in[11];
    const float* WT3  = (const float*)d_in[12];
    const float* Ws1  = (const float*)d_in[13];
    const float* bs1  = (const float*)d_in[14];
    const float* Ws2  = (const float*)d_in[15];
    const float* bs2  = (const float*)d_in[16];
    const float* Wv   = (const float*)d_in[17];
    const float* cM1  = (const float*)d_in[18];
    const float* cM2  = (const float*)d_in[19];
    const float* cM3  = (const float*)d_in[20];

    const int N = in_sizes[0] / 128;
    u16* wbf = (u16*)d_ws;

    mp_prep<<<512, 256, 0, stream>>>(Wq1, Wq2, WT1, WT2, WT3, Ws1, Ws2, Wv, wbf);

    const int nblk = (N + 31) / 32;
    mp_main<<<nblk, 128, 0, stream>>>(feat, mu, T0, T1, T2, T3,
                                      bq1, bq2, bs1, bs2, cM1, cM2, cM3,
                                      wbf, (float*)d_out, N);
}